// Round 1
// baseline (716.989 us; speedup 1.0000x reference)
//
#include <hip/hip_runtime.h>

#define S_LEN 2048
#define HID   768
#define NH    12
#define HD    64
#define BATCH 2

__device__ __forceinline__ void fma4(float4& c, float a, const float4& b) {
    c.x = fmaf(a, b.x, c.x); c.y = fmaf(a, b.y, c.y);
    c.z = fmaf(a, b.z, c.z); c.w = fmaf(a, b.w, c.w);
}
__device__ __forceinline__ float dot4(const float4& a, const float4& b) {
    return a.x*b.x + a.y*b.y + a.z*b.z + a.w*b.w;
}

// ---------------------------------------------------------------------------
// QKV projection: out = X @ W + b, written directly in [B, H, S, HD] layout.
// X: [M=4096, K=768], W: [768, 768] (row k, col n), bias: [768]
// 64x64 block tile, 4x4 per-thread micro-tile, BK=16.
// ---------------------------------------------------------------------------
__global__ __launch_bounds__(256) void qkv_gemm_kernel(
    const float* __restrict__ X, const float* __restrict__ W,
    const float* __restrict__ bias, float* __restrict__ out)
{
    const int K = HID, N = HID;
    __shared__ __align__(16) float As[64][20];   // [m][k], row stride 80B (16B-aligned)
    __shared__ __align__(16) float Bs[16][68];   // [k][n], row stride 272B

    const int tid = threadIdx.x;
    const int bm = blockIdx.y * 64;
    const int bn = blockIdx.x * 64;
    const int tx = tid & 15;        // col group (n0 = tx*4)
    const int ty = tid >> 4;        // row group (m0 = ty*4)

    const int am  = tid >> 2;        // 0..63  staging row for A
    const int ak  = (tid & 3) * 4;   // 0,4,8,12
    const int bk  = tid >> 4;        // 0..15  staging row for B
    const int bn4 = (tid & 15) * 4;  // 0..60

    float4 acc[4];
#pragma unroll
    for (int i = 0; i < 4; i++) acc[i] = make_float4(0.f, 0.f, 0.f, 0.f);

    for (int k0 = 0; k0 < K; k0 += 16) {
        __syncthreads();
        float4 av = *(const float4*)&X[(size_t)(bm + am) * K + k0 + ak];
        float4 bv = *(const float4*)&W[(size_t)(k0 + bk) * N + bn + bn4];
        *(float4*)&As[am][ak]  = av;
        *(float4*)&Bs[bk][bn4] = bv;
        __syncthreads();

#pragma unroll
        for (int kq = 0; kq < 4; kq++) {
            float4 a[4], b[4];
#pragma unroll
            for (int i = 0; i < 4; i++) a[i] = *(const float4*)&As[ty*4 + i][kq*4];
#pragma unroll
            for (int kk = 0; kk < 4; kk++) b[kk] = *(const float4*)&Bs[kq*4 + kk][tx*4];
#pragma unroll
            for (int i = 0; i < 4; i++) {
                fma4(acc[i], a[i].x, b[0]);
                fma4(acc[i], a[i].y, b[1]);
                fma4(acc[i], a[i].z, b[2]);
                fma4(acc[i], a[i].w, b[3]);
            }
        }
    }

    const float4 bb = *(const float4*)&bias[bn + tx*4];
    const int n = bn + tx*4;
    const int h = n / HD;
    const int dd = n % HD;
#pragma unroll
    for (int i = 0; i < 4; i++) {
        const int m  = bm + ty*4 + i;
        const int b_ = m / S_LEN;
        const int s_ = m % S_LEN;
        float4 r = acc[i];
        r.x += bb.x; r.y += bb.y; r.z += bb.z; r.w += bb.w;
        *(float4*)&out[((size_t)(b_*NH + h) * S_LEN + s_) * HD + dd] = r;
    }
}

// ---------------------------------------------------------------------------
// Flash attention, fp32. One block per (b*h, q-tile of 64 rows).
// 256 threads; thread (rg=tid>>4, kg=tid&15) owns rows {rg+16i}, keys {kg+16j},
// d-cols {kg*4..kg*4+3}. Online softmax; 16-lane shfl row reductions.
// P tile overlaid on K tile (KPs). LDS = 3*64*68*4 + 256 = 52.5 KB.
// ---------------------------------------------------------------------------
__global__ __launch_bounds__(256) void attn_kernel(
    const float* __restrict__ Qg, const float* __restrict__ Kg,
    const float* __restrict__ Vg, const float* __restrict__ maskg,
    float* __restrict__ out)
{
    __shared__ __align__(16) float smem[3*64*68 + 64];
    float (*Qs)[68]  = (float(*)[68])smem;
    float (*KPs)[68] = (float(*)[68])(smem + 64*68);
    float (*Vs)[68]  = (float(*)[68])(smem + 2*64*68);
    float* mk = smem + 3*64*68;

    const int tid = threadIdx.x;
    const int bh  = blockIdx.y;           // 0..23
    const int q0  = blockIdx.x * 64;
    const int bi  = bh / NH;
    const int hi  = bh % NH;
    const float* Qh = Qg + (size_t)bh * S_LEN * HD;
    const float* Kh = Kg + (size_t)bh * S_LEN * HD;
    const float* Vh = Vg + (size_t)bh * S_LEN * HD;
    const float* mb = maskg + (size_t)bi * S_LEN;

    const int lr = tid >> 4;         // staging row base 0..15
    const int lc = (tid & 15) * 4;   // staging col

    // Q tile, pre-scaled by 1/sqrt(d)
#pragma unroll
    for (int i = 0; i < 4; i++) {
        const int r = lr + i*16;
        float4 q4 = *(const float4*)&Qh[(size_t)(q0 + r) * HD + lc];
        q4.x *= 0.125f; q4.y *= 0.125f; q4.z *= 0.125f; q4.w *= 0.125f;
        *(float4*)&Qs[r][lc] = q4;
    }

    const int rg = tid >> 4;   // 0..15
    const int kg = tid & 15;   // 0..15

    float m_run[4], l_run[4];
    float4 o[4];
#pragma unroll
    for (int i = 0; i < 4; i++) {
        m_run[i] = -1e30f; l_run[i] = 0.0f;
        o[i] = make_float4(0.f, 0.f, 0.f, 0.f);
    }

    for (int kt = 0; kt < S_LEN / 64; kt++) {
        const int k0 = kt * 64;
        __syncthreads();   // A: prior PV reads of KPs/Vs complete
#pragma unroll
        for (int i = 0; i < 4; i++) {
            const int r = lr + i*16;
            *(float4*)&KPs[r][lc] = *(const float4*)&Kh[(size_t)(k0 + r) * HD + lc];
            *(float4*)&Vs[r][lc]  = *(const float4*)&Vh[(size_t)(k0 + r) * HD + lc];
        }
        if (tid < 64) mk[tid] = mb[k0 + tid];
        __syncthreads();   // B: tiles loaded

        // ---- scores: s[i][j] = q_row(rg+16i) . k_row(kg+16j) + mask ----
        float s[4][4];
#pragma unroll
        for (int i = 0; i < 4; i++)
#pragma unroll
            for (int j = 0; j < 4; j++) s[i][j] = mk[kg + 16*j];

#pragma unroll 4
        for (int x4 = 0; x4 < 16; x4++) {
            float4 q4[4], kv[4];
#pragma unroll
            for (int i = 0; i < 4; i++) q4[i] = *(const float4*)&Qs[rg + 16*i][x4*4];
#pragma unroll
            for (int j = 0; j < 4; j++) kv[j] = *(const float4*)&KPs[kg + 16*j][x4*4];
#pragma unroll
            for (int i = 0; i < 4; i++)
#pragma unroll
                for (int j = 0; j < 4; j++)
                    s[i][j] += dot4(q4[i], kv[j]);
        }

        // ---- online softmax: row max over 4 local + 16-lane group ----
        float alpha[4];
#pragma unroll
        for (int i = 0; i < 4; i++) {
            float pmax = fmaxf(fmaxf(s[i][0], s[i][1]), fmaxf(s[i][2], s[i][3]));
#pragma unroll
            for (int d = 1; d < 16; d <<= 1) pmax = fmaxf(pmax, __shfl_xor(pmax, d, 64));
            const float m_new = fmaxf(m_run[i], pmax);
            alpha[i] = __expf(m_run[i] - m_new);
            m_run[i] = m_new;
        }

        __syncthreads();   // C: all K reads done before P overwrites KPs

        float psum[4];
#pragma unroll
        for (int i = 0; i < 4; i++) {
            float ps = 0.f;
#pragma unroll
            for (int j = 0; j < 4; j++) {
                const float p = __expf(s[i][j] - m_run[i]);
                KPs[rg + 16*i][kg + 16*j] = p;
                ps += p;
            }
#pragma unroll
            for (int d = 1; d < 16; d <<= 1) ps += __shfl_xor(ps, d, 64);
            psum[i] = ps;
        }
#pragma unroll
        for (int i = 0; i < 4; i++) {
            l_run[i] = l_run[i] * alpha[i] + psum[i];
            o[i].x *= alpha[i]; o[i].y *= alpha[i];
            o[i].z *= alpha[i]; o[i].w *= alpha[i];
        }

        __syncthreads();   // D: P tile visible

        // ---- PV: o[row][kg*4..+3] += sum_k P[row][k] * V[k][kg*4..+3] ----
#pragma unroll 4
        for (int k4 = 0; k4 < 16; k4++) {
            float4 p4[4];
#pragma unroll
            for (int i = 0; i < 4; i++) p4[i] = *(const float4*)&KPs[rg + 16*i][k4*4];
            const float4 v0 = *(const float4*)&Vs[k4*4 + 0][kg*4];
            const float4 v1 = *(const float4*)&Vs[k4*4 + 1][kg*4];
            const float4 v2 = *(const float4*)&Vs[k4*4 + 2][kg*4];
            const float4 v3 = *(const float4*)&Vs[k4*4 + 3][kg*4];
#pragma unroll
            for (int i = 0; i < 4; i++) {
                fma4(o[i], p4[i].x, v0);
                fma4(o[i], p4[i].y, v1);
                fma4(o[i], p4[i].z, v2);
                fma4(o[i], p4[i].w, v3);
            }
        }
    }

    // epilogue: out[b, s, h*64 + dcol] = o / l
#pragma unroll
    for (int i = 0; i < 4; i++) {
        const float inv = 1.0f / l_run[i];
        const int r = rg + 16*i;
        float4 res = make_float4(o[i].x*inv, o[i].y*inv, o[i].z*inv, o[i].w*inv);
        *(float4*)&out[((size_t)(bi * S_LEN + q0 + r)) * HID + hi * HD + kg * 4] = res;
    }
}

extern "C" void kernel_launch(void* const* d_in, const int* in_sizes, int n_in,
                              void* d_out, int out_size, void* d_ws, size_t ws_size,
                              hipStream_t stream) {
    const float* X    = (const float*)d_in[0];
    const float* mask = (const float*)d_in[1];
    const float* Wq   = (const float*)d_in[2];
    const float* bq   = (const float*)d_in[3];
    const float* Wk   = (const float*)d_in[4];
    const float* bk   = (const float*)d_in[5];
    const float* Wv   = (const float*)d_in[6];
    const float* bv   = (const float*)d_in[7];
    float* out = (float*)d_out;

    const size_t per = (size_t)BATCH * NH * S_LEN * HD;  // 3,145,728 floats
    float* qws = (float*)d_ws;
    float* kws = qws + per;
    float* vws = kws + per;

    dim3 ggrid(HID / 64, (BATCH * S_LEN) / 64);   // (12, 64)
    qkv_gemm_kernel<<<ggrid, 256, 0, stream>>>(X, Wq, bq, qws);
    qkv_gemm_kernel<<<ggrid, 256, 0, stream>>>(X, Wk, bk, kws);
    qkv_gemm_kernel<<<ggrid, 256, 0, stream>>>(X, Wv, bv, vws);

    dim3 agrid(S_LEN / 64, BATCH * NH);           // (32, 24)
    attn_kernel<<<agrid, 256, 0, stream>>>(qws, kws, vws, mask, out);
}

// Round 3
// 213.261 us; speedup vs baseline: 3.3620x; 3.3620x over previous
//
#include <hip/hip_runtime.h>

#define S_LEN 2048
#define HID   768
#define NH    12
#define HD    64
#define BATCH 2
#define GK    768   // GEMM K dim

typedef __attribute__((ext_vector_type(8))) short bf16x8;
typedef __attribute__((ext_vector_type(4))) float f32x4;
typedef __attribute__((ext_vector_type(4))) short s16x4;
typedef __attribute__((ext_vector_type(8))) short s16x8;

__device__ __forceinline__ unsigned short f2bf(float f) {
    union { float f; unsigned int u; } v; v.f = f;
    unsigned int r = v.u + 0x7fffu + ((v.u >> 16) & 1u);
    return (unsigned short)(r >> 16);
}

// ---------------------------------------------------------------------------
// X [4096,768] fp32 -> bf16
// ---------------------------------------------------------------------------
__global__ __launch_bounds__(256) void convert_x(const float* __restrict__ X,
                                                 unsigned short* __restrict__ Xb) {
    int id = blockIdx.x * 256 + threadIdx.x;   // one float4 per thread
    float4 v = ((const float4*)X)[id];
    s16x4 o; o[0] = (short)f2bf(v.x); o[1] = (short)f2bf(v.y);
    o[2] = (short)f2bf(v.z); o[3] = (short)f2bf(v.w);
    ((s16x4*)Xb)[id] = o;
}

// ---------------------------------------------------------------------------
// Pack Wq|Wk|Wv [768,768] fp32 (k-major) -> Wt [2304][768] bf16 (n-major, k-contig)
// 32x32 tiles via LDS.
// ---------------------------------------------------------------------------
__global__ __launch_bounds__(256) void transpose_w(
    const float* __restrict__ Wq, const float* __restrict__ Wk,
    const float* __restrict__ Wv, unsigned short* __restrict__ Wt) {
    __shared__ float T[32][33];
    int bid = blockIdx.x;
    int mat = bid / 576, t = bid % 576;
    int tk = t / 24, tn = t % 24;
    const float* W = (mat == 0) ? Wq : (mat == 1) ? Wk : Wv;
    int r  = threadIdx.x >> 3;
    int c4 = (threadIdx.x & 7) * 4;
    float4 v = *(const float4*)&W[(size_t)(tk*32 + r) * GK + tn*32 + c4];
    T[c4+0][r] = v.x; T[c4+1][r] = v.y; T[c4+2][r] = v.z; T[c4+3][r] = v.w;
    __syncthreads();
    s16x4 o;
    o[0] = (short)f2bf(T[r][c4+0]); o[1] = (short)f2bf(T[r][c4+1]);
    o[2] = (short)f2bf(T[r][c4+2]); o[3] = (short)f2bf(T[r][c4+3]);
    *(s16x4*)&Wt[(size_t)(mat*768 + tn*32 + r) * GK + tk*32 + c4] = o;
}

// ---------------------------------------------------------------------------
// Fused QKV GEMM: C[4096,2304] = Xb @ Wt^T (+bias), bf16 MFMA 16x16x32.
// 128x128 block tile, BK=64, 4 waves in 2x2, each wave 4x4 of 16x16 MFMAs.
// Writes bf16 Q (pre-scaled 1/8), K, V in [B,H,S,64] layout.
// ---------------------------------------------------------------------------
__global__ __launch_bounds__(256) void gemm_qkv(
    const unsigned short* __restrict__ Xb, const unsigned short* __restrict__ Wt,
    const float* __restrict__ bq, const float* __restrict__ bk,
    const float* __restrict__ bv,
    unsigned short* __restrict__ qb, unsigned short* __restrict__ kb,
    unsigned short* __restrict__ vb) {
    __shared__ __align__(16) unsigned short As[128][72];
    __shared__ __align__(16) unsigned short Bs[128][72];

    const int tid = threadIdx.x;
    const int bm = blockIdx.y * 128;
    const int bn = blockIdx.x * 128;
    const int w = tid >> 6, l = tid & 63, quad = l >> 4, lq = l & 15;
    const int wx = w & 1, wy = w >> 1;

    f32x4 zero = {0.f, 0.f, 0.f, 0.f};
    f32x4 acc[4][4];
#pragma unroll
    for (int mi = 0; mi < 4; mi++)
#pragma unroll
        for (int ni = 0; ni < 4; ni++) acc[mi][ni] = zero;

    for (int k0 = 0; k0 < GK; k0 += 64) {
        __syncthreads();
        // 128 rows x 64 shorts = 1024 chunks of 8 shorts (16B) per tile.
        // 4 iters x 256 threads covers exactly 1024 chunks. (Round-2 bug:
        // previous code issued only 512 chunks -> half of LDS uninitialized.)
#pragma unroll
        for (int i = 0; i < 4; i++) {
            int id = i * 256 + tid;
            int row = id >> 3, k8 = (id & 7) * 8;
            *(s16x8*)&As[row][k8] = *(const s16x8*)&Xb[(size_t)(bm + row) * GK + k0 + k8];
            *(s16x8*)&Bs[row][k8] = *(const s16x8*)&Wt[(size_t)(bn + row) * GK + k0 + k8];
        }
        __syncthreads();
#pragma unroll
        for (int kh = 0; kh < 2; kh++) {
            bf16x8 a[4], b[4];
#pragma unroll
            for (int mi = 0; mi < 4; mi++)
                a[mi] = *(const bf16x8*)&As[wy*64 + mi*16 + lq][kh*32 + quad*8];
#pragma unroll
            for (int ni = 0; ni < 4; ni++)
                b[ni] = *(const bf16x8*)&Bs[wx*64 + ni*16 + lq][kh*32 + quad*8];
#pragma unroll
            for (int mi = 0; mi < 4; mi++)
#pragma unroll
                for (int ni = 0; ni < 4; ni++)
                    acc[mi][ni] = __builtin_amdgcn_mfma_f32_16x16x32_bf16(
                        a[mi], b[ni], acc[mi][ni], 0, 0, 0);
        }
    }

    const int mat = bn / 768;   // 768 % 128 == 0: block never straddles matrices
    const float* bias = (mat == 0) ? bq : (mat == 1) ? bk : bv;
    unsigned short* outp = (mat == 0) ? qb : (mat == 1) ? kb : vb;
    const float scl = (mat == 0) ? 0.125f : 1.0f;
    const int nbase = bn % 768;
#pragma unroll
    for (int ni = 0; ni < 4; ni++) {
        int hn = nbase + wx*64 + ni*16 + lq;
        float bval = bias[hn];
        int h = hn >> 6, d = hn & 63;
#pragma unroll
        for (int mi = 0; mi < 4; mi++) {
            int rowb = bm + wy*64 + mi*16 + quad*4;
#pragma unroll
            for (int r = 0; r < 4; r++) {
                int m = rowb + r;
                int b_ = m >> 11, s_ = m & 2047;
                float v = (acc[mi][ni][r] + bval) * scl;
                outp[((size_t)((b_*NH + h) * S_LEN + s_)) * HD + d] = f2bf(v);
            }
        }
    }
}

// ---------------------------------------------------------------------------
// MFMA flash attention. Block = (b*h, 64 q-rows), 4 waves x 16 q-rows.
// QK^T and PV via mfma_f32_16x16x32_bf16; P via per-wave LDS round-trip.
// LDS: Qs/Ks (row=seq, col=d), Vt (row=d, col=key), Ps[wave][16 q][64 key].
// All strides 72 bf16 (144 B) -> 2-way bank aliasing only (free).
// ---------------------------------------------------------------------------
__global__ __launch_bounds__(256) void attn_kernel(
    const unsigned short* __restrict__ Qg, const unsigned short* __restrict__ Kg,
    const unsigned short* __restrict__ Vg, const float* __restrict__ maskg,
    float* __restrict__ out) {
    __shared__ __align__(16) unsigned short Qs[64][72];
    __shared__ __align__(16) unsigned short Ks[64][72];
    __shared__ __align__(16) unsigned short Vt[64][72];
    __shared__ __align__(16) unsigned short Ps[4][16][72];
    __shared__ float mk[64];

    const int tid = threadIdx.x;
    const int w = tid >> 6, l = tid & 63, quad = l >> 4, lq = l & 15;
    const int bh = blockIdx.y;
    const int q0 = blockIdx.x * 64;
    const int bi = bh / NH, hi = bh % NH;
    const unsigned short* Qh = Qg + (size_t)bh * S_LEN * HD;
    const unsigned short* Kh = Kg + (size_t)bh * S_LEN * HD;
    const unsigned short* Vh = Vg + (size_t)bh * S_LEN * HD;
    const float* mb = maskg + (size_t)bi * S_LEN;

    // stage Q tile (already scaled by 1/8 in GEMM epilogue)
#pragma unroll
    for (int i = 0; i < 2; i++) {
        int id = i * 256 + tid;
        int row = id >> 3, c8 = (id & 7) * 8;
        *(s16x8*)&Qs[row][c8] = *(const s16x8*)&Qh[(size_t)(q0 + row) * HD + c8];
    }

    float m_run[4], l_run[4];
    f32x4 zero = {0.f, 0.f, 0.f, 0.f};
    f32x4 o[4];
#pragma unroll
    for (int r = 0; r < 4; r++) { m_run[r] = -1e30f; l_run[r] = 0.f; o[r] = zero; }

    for (int kt = 0; kt < S_LEN / 64; kt++) {
        const int k0 = kt * 64;
        __syncthreads();   // prior iteration's reads of Ks/Vt/mk done
#pragma unroll
        for (int i = 0; i < 2; i++) {
            int id = i * 256 + tid;
            int row = id >> 3, c8 = (id & 7) * 8;
            *(s16x8*)&Ks[row][c8] = *(const s16x8*)&Kh[(size_t)(k0 + row) * HD + c8];
        }
        // V transposed: Vt[d][key]
#pragma unroll
        for (int i = 0; i < 2; i++) {
            int id = i * 256 + tid;
            int d = id & 63, k8 = (id >> 6) * 8;
            s16x8 tv;
#pragma unroll
            for (int j = 0; j < 8; j++)
                tv[j] = (short)Vh[(size_t)(k0 + k8 + j) * HD + d];
            *(s16x8*)&Vt[d][k8] = tv;
        }
        if (tid < 64) mk[tid] = mb[k0 + tid];
        __syncthreads();   // tiles visible

        // ---- QK^T: wave w covers q-rows 16w..16w+15 vs 64 keys ----
        bf16x8 a0 = *(const bf16x8*)&Qs[w*16 + lq][quad*8];
        bf16x8 a1 = *(const bf16x8*)&Qs[w*16 + lq][32 + quad*8];
        f32x4 s[4];
#pragma unroll
        for (int g = 0; g < 4; g++) {
            bf16x8 b0 = *(const bf16x8*)&Ks[g*16 + lq][quad*8];
            bf16x8 b1 = *(const bf16x8*)&Ks[g*16 + lq][32 + quad*8];
            f32x4 z = __builtin_amdgcn_mfma_f32_16x16x32_bf16(a0, b0, zero, 0, 0, 0);
            s[g]     = __builtin_amdgcn_mfma_f32_16x16x32_bf16(a1, b1, z,    0, 0, 0);
        }

        float mv[4];
#pragma unroll
        for (int g = 0; g < 4; g++) mv[g] = mk[g*16 + lq];

        // ---- online softmax; C-layout: row = quad*4+r, col(key) = g*16+lq ----
        float alpha[4];
#pragma unroll
        for (int r = 0; r < 4; r++) {
            float sv[4];
#pragma unroll
            for (int g = 0; g < 4; g++) sv[g] = s[g][r] + mv[g];
            float mx = fmaxf(fmaxf(sv[0], sv[1]), fmaxf(sv[2], sv[3]));
#pragma unroll
            for (int d = 1; d < 16; d <<= 1) mx = fmaxf(mx, __shfl_xor(mx, d, 64));
            float m_new = fmaxf(m_run[r], mx);
            float al = __expf(m_run[r] - m_new);
            float ps = 0.f;
#pragma unroll
            for (int g = 0; g < 4; g++) {
                float p = __expf(sv[g] - m_new);
                ps += p;
                Ps[w][quad*4 + r][g*16 + lq] = f2bf(p);
            }
#pragma unroll
            for (int d = 1; d < 16; d <<= 1) ps += __shfl_xor(ps, d, 64);
            l_run[r] = l_run[r] * al + ps;
            m_run[r] = m_new;
            alpha[r] = al;
        }
#pragma unroll
        for (int ng = 0; ng < 4; ng++)
#pragma unroll
            for (int r = 0; r < 4; r++) o[ng][r] *= alpha[r];

        __syncthreads();   // Ps round-trip ordering

        // ---- PV: A = Ps[w] (16 q x 64 key), B^T = Vt (d x key) ----
        bf16x8 pa0 = *(const bf16x8*)&Ps[w][lq][quad*8];
        bf16x8 pa1 = *(const bf16x8*)&Ps[w][lq][32 + quad*8];
#pragma unroll
        for (int ng = 0; ng < 4; ng++) {
            bf16x8 v0 = *(const bf16x8*)&Vt[ng*16 + lq][quad*8];
            bf16x8 v1 = *(const bf16x8*)&Vt[ng*16 + lq][32 + quad*8];
            f32x4 t = __builtin_amdgcn_mfma_f32_16x16x32_bf16(pa0, v0, o[ng], 0, 0, 0);
            o[ng]   = __builtin_amdgcn_mfma_f32_16x16x32_bf16(pa1, v1, t,     0, 0, 0);
        }
    }

    // epilogue: out[bi, q, hi*64 + d] fp32
#pragma unroll
    for (int ng = 0; ng < 4; ng++) {
#pragma unroll
        for (int r = 0; r < 4; r++) {
            int row = q0 + w*16 + quad*4 + r;
            float val = o[ng][r] / l_run[r];
            out[((size_t)(bi * S_LEN + row)) * HID + hi*HD + ng*16 + lq] = val;
        }
    }
}

extern "C" void kernel_launch(void* const* d_in, const int* in_sizes, int n_in,
                              void* d_out, int out_size, void* d_ws, size_t ws_size,
                              hipStream_t stream) {
    const float* X    = (const float*)d_in[0];
    const float* mask = (const float*)d_in[1];
    const float* Wq   = (const float*)d_in[2];
    const float* bq   = (const float*)d_in[3];
    const float* Wk   = (const float*)d_in[4];
    const float* bk   = (const float*)d_in[5];
    const float* Wv   = (const float*)d_in[6];
    const float* bv   = (const float*)d_in[7];
    float* out = (float*)d_out;

    const size_t per = (size_t)BATCH * NH * S_LEN * HD;  // 3,145,728
    unsigned short* qb = (unsigned short*)d_ws;
    unsigned short* kb = qb + per;
    unsigned short* vb = kb + per;
    unsigned short* xb = vb + per;                        // 4096*768
    unsigned short* wt = xb + (size_t)4096 * GK;          // 2304*768

    convert_x<<<3072, 256, 0, stream>>>(X, xb);
    transpose_w<<<1728, 256, 0, stream>>>(Wq, Wk, Wv, wt);

    dim3 ggrid(2304 / 128, 4096 / 128);   // (18, 32)
    gemm_qkv<<<ggrid, 256, 0, stream>>>(xb, wt, bq, bk, bv, qb, kb, vb);

    dim3 agrid(S_LEN / 64, BATCH * NH);   // (32, 24)
    attn_kernel<<<agrid, 256, 0, stream>>>(qb, kb, vb, mask, out);
}